// Round 20
// baseline (101.804 us; speedup 1.0000x reference)
//
#include <hip/hip_runtime.h>
#include <hip/hip_bf16.h>

typedef __attribute__((ext_vector_type(8))) short short8;   // 8 bf16 = 4 VGPR
typedef __attribute__((ext_vector_type(4))) short short4v;  // 4 bf16 = 8B
typedef __attribute__((ext_vector_type(4))) float f32x4;

// Problem dims (fixed by reference)
constexpr int Bb = 8;
constexpr int Dd = 64;
constexpr int Tt = 8192;
constexpr int Kk = 1024;
constexpr int BT = Bb * Tt;            // 65536 rows
constexpr int NTOT = Bb * Dd * Tt;     // 4194304 elements

// Output layout (float32): [codes BT][quantized NTOT][loss 1]
constexpr int OUT_Q_OFF = BT;
constexpr int OUT_LOSS_OFF = BT + NTOT;

// Workspace layout (bytes)
constexpr size_t WS_PREC_OFF  = 0;                        // float[K]       4KB
constexpr size_t WS_PART_OFF  = WS_PREC_OFF + 4096;       // float[1024]    4KB
constexpr size_t WS_CNT_OFF   = WS_PART_OFF + 4096;       // int counter    4KB slot
constexpr size_t WS_EI_OFF    = WS_CNT_OFF + 4096;        // bf16[K][3][64] interleaved, 384KB

// ---- bf16 helpers (RNE, matches numpy/jax) ----
__device__ inline ushort rne_bf16(float v) {
    unsigned u = __float_as_uint(v);
    return (ushort)((u + 0x7FFFu + ((u >> 16) & 1u)) >> 16);
}
__device__ inline float bf16f(ushort h) { return __uint_as_float(((unsigned)h) << 16); }

// ---------------- Kernel PS: prec (blocks 0-3, exact) + split (blocks 4-67) ----
// prec math is BIT-IDENTICAL to the passing r17 prep (sequential 64-fmaf per k)
// — esq must not change even by 1 ulp (t1 rounding-boundary risk). The
// elementwise 3-way split is element-independent -> parallelized over 64
// blocks (4 elems/thread), bit-identical per element. Block 0 also resets the
// cross-block loss counter (runs before the main kernel in stream order).
__global__ void __launch_bounds__(256) prep_kernel(const float* __restrict__ cb,
                                                   float* __restrict__ prec,
                                                   ushort* __restrict__ ei,
                                                   int* __restrict__ counter) {
    if (blockIdx.x < 4) {
        if (blockIdx.x == 0 && threadIdx.x == 0) *counter = 0;
        const int k = blockIdx.x * 256 + threadIdx.x;   // k in [0,1024)
        const float4* row = reinterpret_cast<const float4*>(cb + (size_t)k * Dd);
        float s = 0.f;
#pragma unroll
        for (int i = 0; i < 16; ++i) {
            float4 v = row[i];
            s = fmaf(v.x, v.x, s); s = fmaf(v.y, v.y, s);
            s = fmaf(v.z, v.z, s); s = fmaf(v.w, v.w, s);
        }
        prec[k] = s;
    } else {
        // 64 blocks x 256 threads x 4 elems = 65536 elements
        const int e0 = (blockIdx.x - 4) * 1024 + threadIdx.x * 4;
        const int k = e0 >> 6;
        const int d0 = e0 & 63;
        const float4 v = *reinterpret_cast<const float4*>(cb + e0);
        const float vals[4] = {v.x, v.y, v.z, v.w};
        short4v hv, mv, lv;
#pragma unroll
        for (int j = 0; j < 4; ++j) {
            float x = vals[j];
            ushort h = rne_bf16(x);  float hf = bf16f(h);
            float r1 = x - hf;       ushort m = rne_bf16(r1); float mf = bf16f(m);
            float r2 = r1 - mf;      ushort l = rne_bf16(r2);
            hv[j] = (short)h; mv[j] = (short)m; lv[j] = (short)l;
        }
        const size_t base = (size_t)k * 192 + d0;
        *reinterpret_cast<short4v*>(ei + base + 0)   = hv;   // plane h
        *reinterpret_cast<short4v*>(ei + base + 64)  = mv;   // plane m
        *reinterpret_cast<short4v*>(ei + base + 128) = lv;   // plane l
    }
}

// ---------------- Kernel A: fused split-MFMA GEMM + argmin + quant + loss ----
// EXACTLY the r17 structure (verified optimum: 74.3us kernel): r9 k-loop with
// Bc/Bn prefetch, 6-pass split 16x16x32 MFMA (4 independent 12-deep chains),
// interleaved-B one-base loads, reference-order fp32 score
// s = fp32(t1 - 2*dot), t1 = fp32(zsq+esq), tie -> lowest k; fused quant+loss
// tail (z reconstructed from its 3-way split, err ~2^-27|z|, loss-only).
// NEW: last-finishing block performs the final 1024-partial loss reduce in the
// SAME fixed order as the old loss_kernel (deterministic regardless of which
// block wins) — removes one kernel launch. setprio removed (r19: noise).
constexpr int TM = 64;              // rows per block
constexpr int NKT = Kk / 64;        // 16 k-tiles

__global__ void __launch_bounds__(256, 2) mfma_argmin_kernel(
    const float* __restrict__ z, const float* __restrict__ cb,
    const ushort* __restrict__ ei,
    const float* __restrict__ prec, float* __restrict__ out,
    float* __restrict__ partials, int* __restrict__ counter)
{
    // z tile, 3 planes, swizzled: [split][row][d], row stride 128B, byte ^= (row&7)<<4
    __shared__ __align__(16) ushort z_lds[3 * 64 * 64];   // 24 KB
    __shared__ float zsq_part[4][64];                     // reused as 256-red
    __shared__ float zsq_lds[64];
    __shared__ float red_v[4][64];
    __shared__ int   red_i[4][64];
    __shared__ int   codes_lds[64];
    __shared__ int   last_flag;

    const int tid = threadIdx.x;
    const int lane = tid & 63;
    const int w = tid >> 6;                 // wave 0..3 -> k-slice w*16..+16
    const int row0 = blockIdx.x * TM;
    const int b = row0 >> 13;
    const int t0 = row0 & (Tt - 1);

    // ---- stage z: read [d][t] coalesced, 3-way split, write transposed+swizzled
    {
        const int tt = tid & 63;            // row within tile
        const int dg = tid >> 6;            // d-group: d = dg*16 .. +16
        const float* zp = z + (size_t)b * (Dd * Tt) + (size_t)(dg * 16) * Tt + (t0 + tt);
        float vals[16];
        float psum = 0.f;
#pragma unroll
        for (int i = 0; i < 16; ++i) {
            float v = zp[(size_t)i * Tt];
            vals[i] = v;
            psum = fmaf(v, v, psum);
        }
        zsq_part[dg][tt] = psum;
#pragma unroll
        for (int g = 0; g < 2; ++g) {
            short8 hv, mv, lv;
#pragma unroll
            for (int j = 0; j < 8; ++j) {
                float v = vals[g * 8 + j];
                ushort h = rne_bf16(v);  float hf = bf16f(h);
                float r1 = v - hf;       ushort m = rne_bf16(r1); float mf = bf16f(m);
                float r2 = r1 - mf;      ushort l = rne_bf16(r2);
                hv[j] = (short)h; mv[j] = (short)m; lv[j] = (short)l;
            }
            const int byte_in_row = dg * 32 + g * 16;     // d0*2
            const int sw = tt * 128 + (byte_in_row ^ ((tt & 7) << 4));
            *reinterpret_cast<short8*>((char*)z_lds + 0 * 8192 + sw) = hv;
            *reinterpret_cast<short8*>((char*)z_lds + 1 * 8192 + sw) = mv;
            *reinterpret_cast<short8*>((char*)z_lds + 2 * 8192 + sw) = lv;
        }
    }
    __syncthreads();
    if (tid < 64)
        zsq_lds[tid] = ((zsq_part[0][tid] + zsq_part[1][tid]) + zsq_part[2][tid]) + zsq_part[3][tid];
    __syncthreads();

    // ---- A fragments into registers (once)
    short8 A[3][2][4];   // [plane][dstep][rf]
#pragma unroll
    for (int sA = 0; sA < 3; ++sA)
#pragma unroll
        for (int ds = 0; ds < 2; ++ds)
#pragma unroll
            for (int rf = 0; rf < 4; ++rf) {
                const int row = rf * 16 + (lane & 15);
                const int dby = ds * 64 + ((lane >> 4) * 16);
                A[sA][ds][rf] = *reinterpret_cast<const short8*>(
                    (char*)z_lds + sA * 8192 + row * 128 + (dby ^ ((row & 7) << 4)));
            }

    // per-lane row-set zsq: row = rf*16 + (lane>>4)*4 + j
    float zsq_r[16];
#pragma unroll
    for (int rf = 0; rf < 4; ++rf)
#pragma unroll
        for (int j = 0; j < 4; ++j)
            zsq_r[rf * 4 + j] = zsq_lds[rf * 16 + (lane >> 4) * 4 + j];

    float bestv[16];
    int   besti[16];
#pragma unroll
    for (int i = 0; i < 16; ++i) { bestv[i] = 3.4e38f; besti[i] = 0; }

    const int kl = lane & 15;
    const int d16b = (lane >> 4) * 16;      // byte offset of this lane's d-chunk

    // B fragment loads: ONE base per tile + imm offsets.
    // Bc[p*2+ds] = plane p (h,m,l), dstep ds -> imm = p*128 + ds*64.
    short8 Bc[6];
    float esqc;
    {
        const size_t kg = (size_t)(w * 16 + kl);
        const char* pb = (const char*)ei + kg * 384 + d16b;
        Bc[0] = *reinterpret_cast<const short8*>(pb + 0);
        Bc[1] = *reinterpret_cast<const short8*>(pb + 64);
        Bc[2] = *reinterpret_cast<const short8*>(pb + 128);
        Bc[3] = *reinterpret_cast<const short8*>(pb + 192);
        Bc[4] = *reinterpret_cast<const short8*>(pb + 256);
        Bc[5] = *reinterpret_cast<const short8*>(pb + 320);
        esqc = prec[kg];
    }

    for (int kt = 0; kt < NKT; ++kt) {
        short8 Bn[6];
        float esqn = 0.f;
        if (kt + 1 < NKT) {
            const size_t kg = (size_t)((kt + 1) * 64 + w * 16 + kl);
            const char* pb = (const char*)ei + kg * 384 + d16b;
            Bn[0] = *reinterpret_cast<const short8*>(pb + 0);
            Bn[1] = *reinterpret_cast<const short8*>(pb + 64);
            Bn[2] = *reinterpret_cast<const short8*>(pb + 128);
            Bn[3] = *reinterpret_cast<const short8*>(pb + 192);
            Bn[4] = *reinterpret_cast<const short8*>(pb + 256);
            Bn[5] = *reinterpret_cast<const short8*>(pb + 320);
            esqn = prec[kg];
        }

        f32x4 acc[4];
#pragma unroll
        for (int rf = 0; rf < 4; ++rf) acc[rf] = (f32x4){0.f, 0.f, 0.f, 0.f};

        // pass order identical to r9/r15/r17:
        // per dstep: (zh,eh),(zh,em),(zh,el),(zm,eh),(zm,em),(zl,eh)
#pragma unroll
        for (int ds = 0; ds < 2; ++ds) {
#pragma unroll
            for (int rf = 0; rf < 4; ++rf)
                acc[rf] = __builtin_amdgcn_mfma_f32_16x16x32_bf16(A[0][ds][rf], Bc[0 * 2 + ds], acc[rf], 0, 0, 0);
#pragma unroll
            for (int rf = 0; rf < 4; ++rf)
                acc[rf] = __builtin_amdgcn_mfma_f32_16x16x32_bf16(A[0][ds][rf], Bc[1 * 2 + ds], acc[rf], 0, 0, 0);
#pragma unroll
            for (int rf = 0; rf < 4; ++rf)
                acc[rf] = __builtin_amdgcn_mfma_f32_16x16x32_bf16(A[0][ds][rf], Bc[2 * 2 + ds], acc[rf], 0, 0, 0);
#pragma unroll
            for (int rf = 0; rf < 4; ++rf)
                acc[rf] = __builtin_amdgcn_mfma_f32_16x16x32_bf16(A[1][ds][rf], Bc[0 * 2 + ds], acc[rf], 0, 0, 0);
#pragma unroll
            for (int rf = 0; rf < 4; ++rf)
                acc[rf] = __builtin_amdgcn_mfma_f32_16x16x32_bf16(A[1][ds][rf], Bc[1 * 2 + ds], acc[rf], 0, 0, 0);
#pragma unroll
            for (int rf = 0; rf < 4; ++rf)
                acc[rf] = __builtin_amdgcn_mfma_f32_16x16x32_bf16(A[2][ds][rf], Bc[0 * 2 + ds], acc[rf], 0, 0, 0);
        }

        // epilogue: score + running argmin (this lane's k = kglob for all 16 C-slots)
        const int kglob = kt * 64 + w * 16 + kl;
#pragma unroll
        for (int rf = 0; rf < 4; ++rf)
#pragma unroll
            for (int j = 0; j < 4; ++j) {
                const float t1 = zsq_r[rf * 4 + j] + esqc;       // round(zsq+esq)
                const float s = fmaf(-2.f, acc[rf][j], t1);      // round(t1-2dot)
                if (s < bestv[rf * 4 + j]) { bestv[rf * 4 + j] = s; besti[rf * 4 + j] = kglob; }
            }

        if (kt + 1 < NKT) {
#pragma unroll
            for (int i = 0; i < 6; ++i) Bc[i] = Bn[i];
            esqc = esqn;
        }
    }

    // ---- in-wave reduce over the 16 k-slots (lane&15) per row, tie -> lower k
#pragma unroll
    for (int i = 0; i < 16; ++i) {
#pragma unroll
        for (int m = 1; m < 16; m <<= 1) {
            const float ov = __shfl_xor(bestv[i], m, 16);
            const int   oi = __shfl_xor(besti[i], m, 16);
            if (ov < bestv[i] || (ov == bestv[i] && oi < besti[i])) {
                bestv[i] = ov; besti[i] = oi;
            }
        }
    }
    if ((lane & 15) == 0) {
#pragma unroll
        for (int rf = 0; rf < 4; ++rf)
#pragma unroll
            for (int j = 0; j < 4; ++j) {
                const int row = rf * 16 + (lane >> 4) * 4 + j;
                red_v[w][row] = bestv[rf * 4 + j];
                red_i[w][row] = besti[rf * 4 + j];
            }
    }
    __syncthreads();
    if (tid < 64) {
        float bv = red_v[0][tid];
        int   bi = red_i[0][tid];
#pragma unroll
        for (int s2 = 1; s2 < 4; ++s2) {
            const float v = red_v[s2][tid];
            const int   i = red_i[s2][tid];
            if (v < bv || (v == bv && i < bi)) { bv = v; bi = i; }
        }
        codes_lds[tid] = bi;
        out[row0 + tid] = (float)bi;
    }
    __syncthreads();

    // ---- fused quant + loss tail ----
    // thread (tt, dg): row tt, dims d = dg*16 .. dg*16+15
    {
        const int tt = tid & 63;
        const int dg = tid >> 6;
        const int code = codes_lds[tt];
        const float4* crow = reinterpret_cast<const float4*>(cb + (size_t)code * Dd + dg * 16);
        float4 q4[4];
#pragma unroll
        for (int i = 0; i < 4; ++i) q4[i] = crow[i];
        const float qf[16] = {q4[0].x, q4[0].y, q4[0].z, q4[0].w,
                              q4[1].x, q4[1].y, q4[1].z, q4[1].w,
                              q4[2].x, q4[2].y, q4[2].z, q4[2].w,
                              q4[3].x, q4[3].y, q4[3].z, q4[3].w};
        float* obase = out + OUT_Q_OFF + (size_t)b * (Dd * Tt) + (size_t)(dg * 16) * Tt + (t0 + tt);
        float lacc = 0.f;
#pragma unroll
        for (int g = 0; g < 2; ++g) {
            const int sw = tt * 128 + ((dg * 32 + g * 16) ^ ((tt & 7) << 4));
            const short8 zh8 = *reinterpret_cast<const short8*>((char*)z_lds + 0 * 8192 + sw);
            const short8 zm8 = *reinterpret_cast<const short8*>((char*)z_lds + 1 * 8192 + sw);
            const short8 zl8 = *reinterpret_cast<const short8*>((char*)z_lds + 2 * 8192 + sw);
#pragma unroll
            for (int j = 0; j < 8; ++j) {
                // z reconstructed from its 3-way split: err <= 2^-27|z| (loss-only)
                const float zv = (bf16f((ushort)zh8[j]) + bf16f((ushort)zm8[j])) + bf16f((ushort)zl8[j]);
                const float qv = qf[g * 8 + j];
                const float diff = qv - zv;
                lacc = fmaf(diff, diff, lacc);
                obase[(size_t)(g * 8 + j) * Tt] = qv;   // exact fp32 codebook value
            }
        }
        // block reduce 256 -> 1 (reuse zsq_part as flat float[256])
        float* red256 = &zsq_part[0][0];
        red256[tid] = lacc;
        __syncthreads();
#pragma unroll
        for (int s = 128; s > 0; s >>= 1) {
            if (tid < s) red256[tid] += red256[tid + s];
            __syncthreads();
        }
        if (tid == 0) {
            partials[blockIdx.x] = red256[0];
            __threadfence();                        // publish partial
            const int old = atomicAdd(counter, 1);  // device-scope
            last_flag = (old == 1023);
        }
        __syncthreads();

        // last-finishing block: final 1024-partial reduce, SAME fixed order as
        // the old loss_kernel -> deterministic regardless of which block wins.
        if (last_flag) {
            __threadfence();                        // acquire all partials
            red256[tid] = ((partials[tid] + partials[tid + 256])
                           + partials[tid + 512]) + partials[tid + 768];
            __syncthreads();
#pragma unroll
            for (int s = 128; s > 0; s >>= 1) {
                if (tid < s) red256[tid] += red256[tid + s];
                __syncthreads();
            }
            if (tid == 0)
                out[OUT_LOSS_OFF] = red256[0] * (1.0f / (float)NTOT);
        }
    }
}

extern "C" void kernel_launch(void* const* d_in, const int* in_sizes, int n_in,
                              void* d_out, int out_size, void* d_ws, size_t ws_size,
                              hipStream_t stream) {
    const float* z = (const float*)d_in[0];
    const float* cb = (const float*)d_in[1];
    float* out = (float*)d_out;

    char* ws = (char*)d_ws;
    float* prec = (float*)(ws + WS_PREC_OFF);
    float* partials = (float*)(ws + WS_PART_OFF);
    int* counter = (int*)(ws + WS_CNT_OFF);
    ushort* ei = (ushort*)(ws + WS_EI_OFF);

    prep_kernel<<<68, 256, 0, stream>>>(cb, prec, ei, counter);
    mfma_argmin_kernel<<<BT / TM, 256, 0, stream>>>(z, cb, ei, prec, out, partials, counter);
}

// Round 21
// 74.949 us; speedup vs baseline: 1.3583x; 1.3583x over previous
//
#include <hip/hip_runtime.h>
#include <hip/hip_bf16.h>

typedef __attribute__((ext_vector_type(8))) short short8;   // 8 bf16 = 4 VGPR
typedef __attribute__((ext_vector_type(4))) short short4v;  // 4 bf16 = 8B
typedef __attribute__((ext_vector_type(4))) float f32x4;

// Problem dims (fixed by reference)
constexpr int Bb = 8;
constexpr int Dd = 64;
constexpr int Tt = 8192;
constexpr int Kk = 1024;
constexpr int BT = Bb * Tt;            // 65536 rows
constexpr int NTOT = Bb * Dd * Tt;     // 4194304 elements

// Output layout (float32): [codes BT][quantized NTOT][loss 1]
constexpr int OUT_Q_OFF = BT;
constexpr int OUT_LOSS_OFF = BT + NTOT;

// Workspace layout (bytes)
constexpr size_t WS_PREC_OFF  = 0;                        // float[K]       4KB
constexpr size_t WS_PART_OFF  = WS_PREC_OFF + 4096;       // float[1024]    4KB
constexpr size_t WS_EI_OFF    = WS_PART_OFF + 4096;       // bf16[K][3][64] interleaved, 384KB

// ---- bf16 helpers (RNE, matches numpy/jax) ----
__device__ inline ushort rne_bf16(float v) {
    unsigned u = __float_as_uint(v);
    return (ushort)((u + 0x7FFFu + ((u >> 16) & 1u)) >> 16);
}
__device__ inline float bf16f(ushort h) { return __uint_as_float(((unsigned)h) << 16); }

// ---------------- Kernel PS: prec (blocks 0-3, exact) + split (blocks 4-67) ----
// prec math is BIT-IDENTICAL to the passing r17 prep (sequential 64-fmaf per k)
// — esq must not change even by 1 ulp (t1 rounding-boundary risk). The
// elementwise 3-way split is element-independent -> parallelized over 64
// blocks (4 elems/thread), bit-identical per element.
// (r20 lesson: the last-block loss fusion with __threadfence cost +28us on
// the main kernel — device-scope fences against 16.7MB of in-flight stores
// are NOT cheap. Reverted to the 3-launch structure; widened prep kept.)
__global__ void __launch_bounds__(256) prep_kernel(const float* __restrict__ cb,
                                                   float* __restrict__ prec,
                                                   ushort* __restrict__ ei) {
    if (blockIdx.x < 4) {
        const int k = blockIdx.x * 256 + threadIdx.x;   // k in [0,1024)
        const float4* row = reinterpret_cast<const float4*>(cb + (size_t)k * Dd);
        float s = 0.f;
#pragma unroll
        for (int i = 0; i < 16; ++i) {
            float4 v = row[i];
            s = fmaf(v.x, v.x, s); s = fmaf(v.y, v.y, s);
            s = fmaf(v.z, v.z, s); s = fmaf(v.w, v.w, s);
        }
        prec[k] = s;
    } else {
        // 64 blocks x 256 threads x 4 elems = 65536 elements
        const int e0 = (blockIdx.x - 4) * 1024 + threadIdx.x * 4;
        const int k = e0 >> 6;
        const int d0 = e0 & 63;
        const float4 v = *reinterpret_cast<const float4*>(cb + e0);
        const float vals[4] = {v.x, v.y, v.z, v.w};
        short4v hv, mv, lv;
#pragma unroll
        for (int j = 0; j < 4; ++j) {
            float x = vals[j];
            ushort h = rne_bf16(x);  float hf = bf16f(h);
            float r1 = x - hf;       ushort m = rne_bf16(r1); float mf = bf16f(m);
            float r2 = r1 - mf;      ushort l = rne_bf16(r2);
            hv[j] = (short)h; mv[j] = (short)m; lv[j] = (short)l;
        }
        const size_t base = (size_t)k * 192 + d0;
        *reinterpret_cast<short4v*>(ei + base + 0)   = hv;   // plane h
        *reinterpret_cast<short4v*>(ei + base + 64)  = mv;   // plane m
        *reinterpret_cast<short4v*>(ei + base + 128) = lv;   // plane l
    }
}

// ---------------- Kernel A: fused split-MFMA GEMM + argmin + quant + loss ----
// EXACTLY the r17 structure (verified optimum: 74.3us kernel / 76.8us total):
// r9 k-loop with Bc/Bn prefetch, 6-pass split 16x16x32 MFMA (4 independent
// 12-deep chains), interleaved-B one-base loads, reference-order fp32 score
// s = fp32(t1 - 2*dot), t1 = fp32(zsq+esq), tie -> lowest k; fused quant+loss
// tail (z reconstructed from its 3-way split, err ~2^-27|z|, loss-only);
// per-block partial written plainly, final reduce in a separate kernel.
constexpr int TM = 64;              // rows per block
constexpr int NKT = Kk / 64;        // 16 k-tiles

__global__ void __launch_bounds__(256, 2) mfma_argmin_kernel(
    const float* __restrict__ z, const float* __restrict__ cb,
    const ushort* __restrict__ ei,
    const float* __restrict__ prec, float* __restrict__ out,
    float* __restrict__ partials)
{
    // z tile, 3 planes, swizzled: [split][row][d], row stride 128B, byte ^= (row&7)<<4
    __shared__ __align__(16) ushort z_lds[3 * 64 * 64];   // 24 KB
    __shared__ float zsq_part[4][64];                     // reused as 256-red
    __shared__ float zsq_lds[64];
    __shared__ float red_v[4][64];
    __shared__ int   red_i[4][64];
    __shared__ int   codes_lds[64];

    const int tid = threadIdx.x;
    const int lane = tid & 63;
    const int w = tid >> 6;                 // wave 0..3 -> k-slice w*16..+16
    const int row0 = blockIdx.x * TM;
    const int b = row0 >> 13;
    const int t0 = row0 & (Tt - 1);

    // ---- stage z: read [d][t] coalesced, 3-way split, write transposed+swizzled
    {
        const int tt = tid & 63;            // row within tile
        const int dg = tid >> 6;            // d-group: d = dg*16 .. +16
        const float* zp = z + (size_t)b * (Dd * Tt) + (size_t)(dg * 16) * Tt + (t0 + tt);
        float vals[16];
        float psum = 0.f;
#pragma unroll
        for (int i = 0; i < 16; ++i) {
            float v = zp[(size_t)i * Tt];
            vals[i] = v;
            psum = fmaf(v, v, psum);
        }
        zsq_part[dg][tt] = psum;
#pragma unroll
        for (int g = 0; g < 2; ++g) {
            short8 hv, mv, lv;
#pragma unroll
            for (int j = 0; j < 8; ++j) {
                float v = vals[g * 8 + j];
                ushort h = rne_bf16(v);  float hf = bf16f(h);
                float r1 = v - hf;       ushort m = rne_bf16(r1); float mf = bf16f(m);
                float r2 = r1 - mf;      ushort l = rne_bf16(r2);
                hv[j] = (short)h; mv[j] = (short)m; lv[j] = (short)l;
            }
            const int byte_in_row = dg * 32 + g * 16;     // d0*2
            const int sw = tt * 128 + (byte_in_row ^ ((tt & 7) << 4));
            *reinterpret_cast<short8*>((char*)z_lds + 0 * 8192 + sw) = hv;
            *reinterpret_cast<short8*>((char*)z_lds + 1 * 8192 + sw) = mv;
            *reinterpret_cast<short8*>((char*)z_lds + 2 * 8192 + sw) = lv;
        }
    }
    __syncthreads();
    if (tid < 64)
        zsq_lds[tid] = ((zsq_part[0][tid] + zsq_part[1][tid]) + zsq_part[2][tid]) + zsq_part[3][tid];
    __syncthreads();

    // ---- A fragments into registers (once)
    short8 A[3][2][4];   // [plane][dstep][rf]
#pragma unroll
    for (int sA = 0; sA < 3; ++sA)
#pragma unroll
        for (int ds = 0; ds < 2; ++ds)
#pragma unroll
            for (int rf = 0; rf < 4; ++rf) {
                const int row = rf * 16 + (lane & 15);
                const int dby = ds * 64 + ((lane >> 4) * 16);
                A[sA][ds][rf] = *reinterpret_cast<const short8*>(
                    (char*)z_lds + sA * 8192 + row * 128 + (dby ^ ((row & 7) << 4)));
            }

    // per-lane row-set zsq: row = rf*16 + (lane>>4)*4 + j
    float zsq_r[16];
#pragma unroll
    for (int rf = 0; rf < 4; ++rf)
#pragma unroll
        for (int j = 0; j < 4; ++j)
            zsq_r[rf * 4 + j] = zsq_lds[rf * 16 + (lane >> 4) * 4 + j];

    float bestv[16];
    int   besti[16];
#pragma unroll
    for (int i = 0; i < 16; ++i) { bestv[i] = 3.4e38f; besti[i] = 0; }

    const int kl = lane & 15;
    const int d16b = (lane >> 4) * 16;      // byte offset of this lane's d-chunk

    // B fragment loads: ONE base per tile + imm offsets.
    // Bc[p*2+ds] = plane p (h,m,l), dstep ds -> imm = p*128 + ds*64.
    short8 Bc[6];
    float esqc;
    {
        const size_t kg = (size_t)(w * 16 + kl);
        const char* pb = (const char*)ei + kg * 384 + d16b;
        Bc[0] = *reinterpret_cast<const short8*>(pb + 0);
        Bc[1] = *reinterpret_cast<const short8*>(pb + 64);
        Bc[2] = *reinterpret_cast<const short8*>(pb + 128);
        Bc[3] = *reinterpret_cast<const short8*>(pb + 192);
        Bc[4] = *reinterpret_cast<const short8*>(pb + 256);
        Bc[5] = *reinterpret_cast<const short8*>(pb + 320);
        esqc = prec[kg];
    }

    for (int kt = 0; kt < NKT; ++kt) {
        short8 Bn[6];
        float esqn = 0.f;
        if (kt + 1 < NKT) {
            const size_t kg = (size_t)((kt + 1) * 64 + w * 16 + kl);
            const char* pb = (const char*)ei + kg * 384 + d16b;
            Bn[0] = *reinterpret_cast<const short8*>(pb + 0);
            Bn[1] = *reinterpret_cast<const short8*>(pb + 64);
            Bn[2] = *reinterpret_cast<const short8*>(pb + 128);
            Bn[3] = *reinterpret_cast<const short8*>(pb + 192);
            Bn[4] = *reinterpret_cast<const short8*>(pb + 256);
            Bn[5] = *reinterpret_cast<const short8*>(pb + 320);
            esqn = prec[kg];
        }

        f32x4 acc[4];
#pragma unroll
        for (int rf = 0; rf < 4; ++rf) acc[rf] = (f32x4){0.f, 0.f, 0.f, 0.f};

        // pass order identical to r9/r15/r17:
        // per dstep: (zh,eh),(zh,em),(zh,el),(zm,eh),(zm,em),(zl,eh)
#pragma unroll
        for (int ds = 0; ds < 2; ++ds) {
#pragma unroll
            for (int rf = 0; rf < 4; ++rf)
                acc[rf] = __builtin_amdgcn_mfma_f32_16x16x32_bf16(A[0][ds][rf], Bc[0 * 2 + ds], acc[rf], 0, 0, 0);
#pragma unroll
            for (int rf = 0; rf < 4; ++rf)
                acc[rf] = __builtin_amdgcn_mfma_f32_16x16x32_bf16(A[0][ds][rf], Bc[1 * 2 + ds], acc[rf], 0, 0, 0);
#pragma unroll
            for (int rf = 0; rf < 4; ++rf)
                acc[rf] = __builtin_amdgcn_mfma_f32_16x16x32_bf16(A[0][ds][rf], Bc[2 * 2 + ds], acc[rf], 0, 0, 0);
#pragma unroll
            for (int rf = 0; rf < 4; ++rf)
                acc[rf] = __builtin_amdgcn_mfma_f32_16x16x32_bf16(A[1][ds][rf], Bc[0 * 2 + ds], acc[rf], 0, 0, 0);
#pragma unroll
            for (int rf = 0; rf < 4; ++rf)
                acc[rf] = __builtin_amdgcn_mfma_f32_16x16x32_bf16(A[1][ds][rf], Bc[1 * 2 + ds], acc[rf], 0, 0, 0);
#pragma unroll
            for (int rf = 0; rf < 4; ++rf)
                acc[rf] = __builtin_amdgcn_mfma_f32_16x16x32_bf16(A[2][ds][rf], Bc[0 * 2 + ds], acc[rf], 0, 0, 0);
        }

        // epilogue: score + running argmin (this lane's k = kglob for all 16 C-slots)
        const int kglob = kt * 64 + w * 16 + kl;
#pragma unroll
        for (int rf = 0; rf < 4; ++rf)
#pragma unroll
            for (int j = 0; j < 4; ++j) {
                const float t1 = zsq_r[rf * 4 + j] + esqc;       // round(zsq+esq)
                const float s = fmaf(-2.f, acc[rf][j], t1);      // round(t1-2dot)
                if (s < bestv[rf * 4 + j]) { bestv[rf * 4 + j] = s; besti[rf * 4 + j] = kglob; }
            }

        if (kt + 1 < NKT) {
#pragma unroll
            for (int i = 0; i < 6; ++i) Bc[i] = Bn[i];
            esqc = esqn;
        }
    }

    // ---- in-wave reduce over the 16 k-slots (lane&15) per row, tie -> lower k
#pragma unroll
    for (int i = 0; i < 16; ++i) {
#pragma unroll
        for (int m = 1; m < 16; m <<= 1) {
            const float ov = __shfl_xor(bestv[i], m, 16);
            const int   oi = __shfl_xor(besti[i], m, 16);
            if (ov < bestv[i] || (ov == bestv[i] && oi < besti[i])) {
                bestv[i] = ov; besti[i] = oi;
            }
        }
    }
    if ((lane & 15) == 0) {
#pragma unroll
        for (int rf = 0; rf < 4; ++rf)
#pragma unroll
            for (int j = 0; j < 4; ++j) {
                const int row = rf * 16 + (lane >> 4) * 4 + j;
                red_v[w][row] = bestv[rf * 4 + j];
                red_i[w][row] = besti[rf * 4 + j];
            }
    }
    __syncthreads();
    if (tid < 64) {
        float bv = red_v[0][tid];
        int   bi = red_i[0][tid];
#pragma unroll
        for (int s2 = 1; s2 < 4; ++s2) {
            const float v = red_v[s2][tid];
            const int   i = red_i[s2][tid];
            if (v < bv || (v == bv && i < bi)) { bv = v; bi = i; }
        }
        codes_lds[tid] = bi;
        out[row0 + tid] = (float)bi;
    }
    __syncthreads();

    // ---- fused quant + loss tail ----
    // thread (tt, dg): row tt, dims d = dg*16 .. dg*16+15
    {
        const int tt = tid & 63;
        const int dg = tid >> 6;
        const int code = codes_lds[tt];
        const float4* crow = reinterpret_cast<const float4*>(cb + (size_t)code * Dd + dg * 16);
        float4 q4[4];
#pragma unroll
        for (int i = 0; i < 4; ++i) q4[i] = crow[i];
        const float qf[16] = {q4[0].x, q4[0].y, q4[0].z, q4[0].w,
                              q4[1].x, q4[1].y, q4[1].z, q4[1].w,
                              q4[2].x, q4[2].y, q4[2].z, q4[2].w,
                              q4[3].x, q4[3].y, q4[3].z, q4[3].w};
        float* obase = out + OUT_Q_OFF + (size_t)b * (Dd * Tt) + (size_t)(dg * 16) * Tt + (t0 + tt);
        float lacc = 0.f;
#pragma unroll
        for (int g = 0; g < 2; ++g) {
            const int sw = tt * 128 + ((dg * 32 + g * 16) ^ ((tt & 7) << 4));
            const short8 zh8 = *reinterpret_cast<const short8*>((char*)z_lds + 0 * 8192 + sw);
            const short8 zm8 = *reinterpret_cast<const short8*>((char*)z_lds + 1 * 8192 + sw);
            const short8 zl8 = *reinterpret_cast<const short8*>((char*)z_lds + 2 * 8192 + sw);
#pragma unroll
            for (int j = 0; j < 8; ++j) {
                // z reconstructed from its 3-way split: err <= 2^-27|z| (loss-only)
                const float zv = (bf16f((ushort)zh8[j]) + bf16f((ushort)zm8[j])) + bf16f((ushort)zl8[j]);
                const float qv = qf[g * 8 + j];
                const float diff = qv - zv;
                lacc = fmaf(diff, diff, lacc);
                obase[(size_t)(g * 8 + j) * Tt] = qv;   // exact fp32 codebook value
            }
        }
        // block reduce 256 -> 1 (reuse zsq_part as flat float[256])
        float* red256 = &zsq_part[0][0];
        red256[tid] = lacc;
        __syncthreads();
#pragma unroll
        for (int s = 128; s > 0; s >>= 1) {
            if (tid < s) red256[tid] += red256[tid + s];
            __syncthreads();
        }
        if (tid == 0) partials[blockIdx.x] = red256[0];
    }
}

// ---------------- Kernel C: final loss reduce (1024 partials) ----------------
__global__ void __launch_bounds__(256) loss_kernel(const float* __restrict__ partials,
                                                   float* __restrict__ out) {
    __shared__ float red[256];
    const int t = threadIdx.x;
    red[t] = ((partials[t] + partials[t + 256]) + partials[t + 512]) + partials[t + 768];
    __syncthreads();
#pragma unroll
    for (int s = 128; s > 0; s >>= 1) {
        if (t < s) red[t] += red[t + s];
        __syncthreads();
    }
    if (t == 0)
        out[OUT_LOSS_OFF] = red[0] * (1.0f / (float)NTOT);
}

extern "C" void kernel_launch(void* const* d_in, const int* in_sizes, int n_in,
                              void* d_out, int out_size, void* d_ws, size_t ws_size,
                              hipStream_t stream) {
    const float* z = (const float*)d_in[0];
    const float* cb = (const float*)d_in[1];
    float* out = (float*)d_out;

    char* ws = (char*)d_ws;
    float* prec = (float*)(ws + WS_PREC_OFF);
    float* partials = (float*)(ws + WS_PART_OFF);
    ushort* ei = (ushort*)(ws + WS_EI_OFF);

    prep_kernel<<<68, 256, 0, stream>>>(cb, prec, ei);
    mfma_argmin_kernel<<<BT / TM, 256, 0, stream>>>(z, cb, ei, prec, out, partials);
    loss_kernel<<<1, 256, 0, stream>>>(partials, out);
}